// Round 1
// baseline (610.227 us; speedup 1.0000x reference)
//
#include <hip/hip_runtime.h>
#include <math.h>

typedef short v8s __attribute__((ext_vector_type(8)));
typedef float v4f __attribute__((ext_vector_type(4)));

#define NVOX 64000      // 40^3
#define NPAD 74088      // 42^3
#define P2   1764       // 42^2
#define GSTR 592704     // NPAD*8

__device__ __forceinline__ unsigned short bf16rne(float f){
  unsigned int u = __float_as_uint(f);
  u += 0x7FFFu + ((u >> 16) & 1u);
  return (unsigned short)(u >> 16);
}

// ---------------- projection: xp = proj_w @ x ; write fp32 [c][n] and bf16 padded [g][p][8c]
__global__ __launch_bounds__(256) void proj_k(const float* __restrict__ x,
                                              const float* __restrict__ pw,
                                              float* __restrict__ xp,
                                              short* __restrict__ xpt){
  __shared__ float s_pw[4096];
  int tid = threadIdx.x;
  for (int j = tid; j < 4096; j += 256) s_pw[j] = pw[j];
  __syncthreads();
  int m = blockIdx.x * 256 + tid;
  float xv[64];
#pragma unroll
  for (int i = 0; i < 64; i++) xv[i] = x[(size_t)i * NVOX + m];
  int d = m / 1600; int r = m - d * 1600; int h = r / 40; int w = r - h * 40;
  int p = ((d + 1) * 42 + (h + 1)) * 42 + (w + 1);
  const float4* s4 = reinterpret_cast<const float4*>(s_pw);
  for (int g8 = 0; g8 < 8; g8++){
    v8s pk;
#pragma unroll
    for (int j = 0; j < 8; j++){
      int co = g8 * 8 + j;
      float acc = 0.f;
#pragma unroll
      for (int i4 = 0; i4 < 16; i4++){
        float4 pv = s4[co * 16 + i4];
        acc = fmaf(pv.x, xv[i4*4+0], acc);
        acc = fmaf(pv.y, xv[i4*4+1], acc);
        acc = fmaf(pv.z, xv[i4*4+2], acc);
        acc = fmaf(pv.w, xv[i4*4+3], acc);
      }
      xp[(size_t)co * NVOX + m] = acc;
      pk[j] = (short)bf16rne(acc);
    }
    *(v8s*)(xpt + (size_t)g8 * GSTR + (size_t)p * 8) = pk;
  }
}

// ---------------- base_w fp32 (o,c,t) -> bf16 [t][o][c]
__global__ void bwprep_k(const float* __restrict__ bw, short* __restrict__ bwb){
  int e = blockIdx.x * 256 + threadIdx.x;           // 0 .. 110591
  int t = e >> 12; int rem = e & 4095;
  int o = rem >> 6; int c = rem & 63;
  bwb[e] = (short)bf16rne(bw[(o * 64 + c) * 27 + t]);
}

// ---------------- separable 3x3x3 box sums (zero pad), /27 on last pass
__global__ void boxw_k(const float* __restrict__ in, float* __restrict__ out){
  int g = blockIdx.x * 256 + threadIdx.x;
  int w = g % 40;
  float s = in[g];
  if (w > 0)  s += in[g - 1];
  if (w < 39) s += in[g + 1];
  out[g] = s;
}
__global__ void boxh_k(const float* __restrict__ in, float* __restrict__ out){
  int g = blockIdx.x * 256 + threadIdx.x;
  int h = (g / 40) % 40;
  float s = in[g];
  if (h > 0)  s += in[g - 40];
  if (h < 39) s += in[g + 40];
  out[g] = s;
}
__global__ void boxd_k(const float* __restrict__ in, float* __restrict__ out){
  int g = blockIdx.x * 256 + threadIdx.x;
  int d = (g / 1600) % 40;
  float s = in[g];
  if (d > 0)  s += in[g - 1600];
  if (d < 39) s += in[g + 1600];
  out[g] = s * (1.f / 27.f);
}

// ---------------- kmeans init: slot0 = first 4 points with cnt=1; zero slots 1..11
__global__ void kinit_k(const float* __restrict__ xm, float* __restrict__ km){
  int t = threadIdx.x;
  if (t < 256) km[t] = xm[(size_t)(t & 63) * NVOX + (t >> 6)];
  if (t < 4) km[256 + t] = 1.f;
  for (int j = 260 + t; j < 12 * 260; j += 256) km[j] = 0.f;
}

// ---------------- kmeans assign (+reduce into next slot, or write idx)
__global__ __launch_bounds__(256) void assign_k(const float* __restrict__ xm,
                                                const float* __restrict__ kin,
                                                float* __restrict__ kout,
                                                int* __restrict__ idx, int mode){
  __shared__ float s_cent[256];
  __shared__ float s_cc[4];
  __shared__ float s_red[260];
  int t = threadIdx.x;
  s_cent[t] = kin[t] / fmaxf(kin[256 + (t >> 6)], 1.f);
  for (int j = t; j < 260; j += 256) s_red[j] = 0.f;
  __syncthreads();
  if (t < 4){
    float s = 0.f;
    for (int c = 0; c < 64; c++){ float v = s_cent[t * 64 + c]; s = fmaf(v, v, s); }
    s_cc[t] = s;
  }
  __syncthreads();
  int n = blockIdx.x * 256 + t;
  float xv[64];
#pragma unroll
  for (int c = 0; c < 64; c++) xv[c] = xm[(size_t)c * NVOX + n];
  float d0 = 0.f, d1 = 0.f, d2 = 0.f, d3 = 0.f;
#pragma unroll
  for (int c = 0; c < 64; c++){
    float v = xv[c];
    d0 = fmaf(v, s_cent[c], d0);
    d1 = fmaf(v, s_cent[64 + c], d1);
    d2 = fmaf(v, s_cent[128 + c], d2);
    d3 = fmaf(v, s_cent[192 + c], d3);
  }
  float sc0 = s_cc[0] - 2.f * d0;
  float sc1 = s_cc[1] - 2.f * d1;
  float sc2 = s_cc[2] - 2.f * d2;
  float sc3 = s_cc[3] - 2.f * d3;
  int kb = 0; float bs = sc0;
  if (sc1 < bs){ bs = sc1; kb = 1; }
  if (sc2 < bs){ bs = sc2; kb = 2; }
  if (sc3 < bs){ bs = sc3; kb = 3; }
  if (mode){
    idx[n] = kb;
  } else {
#pragma unroll
    for (int c = 0; c < 64; c++) atomicAdd(&s_red[kb * 64 + c], xv[c]);
    atomicAdd(&s_red[256 + kb], 1.f);
    __syncthreads();
    for (int j = t; j < 260; j += 256) atomicAdd(&kout[j], s_red[j]);
  }
}

// ---------------- gating MLPs (1 block, 256 thr)
__global__ void mlp_k(const float* __restrict__ km10,
                      const float* __restrict__ w1, const float* __restrict__ b1,
                      const float* __restrict__ w2, const float* __restrict__ b2,
                      const float* __restrict__ w3, const float* __restrict__ b3,
                      const float* __restrict__ u1, const float* __restrict__ c1,
                      const float* __restrict__ u2, const float* __restrict__ c2,
                      const float* __restrict__ u3, const float* __restrict__ c3,
                      float* __restrict__ wi, float* __restrict__ bias){
  __shared__ float s_feat[256], s_h1[128], s_h2[128], s_g1[64], s_g2[64];
  int t = threadIdx.x;
  s_feat[t] = km10[t] / fmaxf(km10[256 + (t >> 6)], 1.f);
  __syncthreads();
  if (t < 128){
    float z = b1[t];
    for (int i = 0; i < 256; i++) z = fmaf(s_feat[i], w1[i * 128 + t], z);
    s_h1[t] = fmaxf(z, 0.f);
  }
  __syncthreads();
  if (t < 128){
    float z = b2[t];
    for (int i = 0; i < 128; i++) z = fmaf(s_h1[i], w2[i * 128 + t], z);
    s_h2[t] = fmaxf(z, 0.f);
  }
  __syncthreads();
  if (t < 108){
    float z = b3[t];
    for (int i = 0; i < 128; i++) z = fmaf(s_h2[i], w3[i * 108 + t], z);
    wi[t] = 1.f / (1.f + expf(-z));
  }
  if (t < 64){
    float z = c1[t];
    for (int i = 0; i < 256; i++) z = fmaf(s_feat[i], u1[i * 64 + t], z);
    s_g1[t] = fmaxf(z, 0.f);
  }
  __syncthreads();
  if (t < 64){
    float z = c2[t];
    for (int i = 0; i < 64; i++) z = fmaf(s_g1[i], u2[i * 64 + t], z);
    s_g2[t] = fmaxf(z, 0.f);
  }
  __syncthreads();
  {
    float z = c3[t];
    for (int i = 0; i < 64; i++) z = fmaf(s_g2[i], u3[i * 256 + t], z);
    bias[t] = z;
  }
}

// ---------------- main dynamic conv: MFMA bf16, per-tap post-scale by w_i[idx[n]][t]
__global__ __launch_bounds__(128) void conv_k(const short* __restrict__ xpt,
                                              const short* __restrict__ bwb,
                                              const float* __restrict__ wi,
                                              const float* __restrict__ bias,
                                              const int* __restrict__ idx,
                                              const float* __restrict__ x,
                                              const float* __restrict__ pa,
                                              float* __restrict__ out){
  __shared__ float s_wi[108];
  __shared__ float s_bias[256];
  __shared__ int s_poff[27];
  int tid = threadIdx.x;
  for (int j = tid; j < 108; j += 128) s_wi[j] = wi[j];
  for (int j = tid; j < 256; j += 128) s_bias[j] = bias[j];
  if (tid < 27){
    int dz = tid / 9 - 1, dy = (tid / 3) % 3 - 1, dx = tid % 3 - 1;
    s_poff[tid] = dz * P2 + dy * 42 + dx;
  }
  __syncthreads();
  int wv = tid >> 6, lane = tid & 63;
  int col = lane & 15, kg = lane >> 4;
  int vb = blockIdx.x * 128 + wv * 64;
  int p4[4], wix4[4], ki4[4];
#pragma unroll
  for (int nt = 0; nt < 4; nt++){
    int v = vb + nt * 16 + col;
    int d = v / 1600; int r = v - d * 1600; int h = r / 40; int w = r - h * 40;
    p4[nt] = ((d + 1) * 42 + (h + 1)) * 42 + (w + 1);
    int k = idx[v];
    ki4[nt] = k; wix4[nt] = k * 27;
  }
  v4f acc[4][4];
#pragma unroll
  for (int mt = 0; mt < 4; mt++)
#pragma unroll
    for (int nt = 0; nt < 4; nt++) acc[mt][nt] = (v4f){0.f, 0.f, 0.f, 0.f};
  int aoff[4];
#pragma unroll
  for (int mt = 0; mt < 4; mt++) aoff[mt] = ((mt * 16 + col) << 6) + (kg << 3);
  v4f zero = {0.f, 0.f, 0.f, 0.f};
#pragma unroll
  for (int kc = 0; kc < 2; kc++){
    const short* bw_kc = bwb + kc * 32;
    size_t gbase = (size_t)(kc * 4 + kg) * GSTR;
    for (int t = 0; t < 27; t++){
      int poff = s_poff[t];
      v8s a[4], b[4];
#pragma unroll
      for (int mt = 0; mt < 4; mt++) a[mt] = *(const v8s*)(bw_kc + t * 4096 + aoff[mt]);
#pragma unroll
      for (int nt = 0; nt < 4; nt++) b[nt] = *(const v8s*)(xpt + gbase + (size_t)(p4[nt] + poff) * 8);
#pragma unroll
      for (int nt = 0; nt < 4; nt++){
        float wk = s_wi[wix4[nt] + t];
#pragma unroll
        for (int mt = 0; mt < 4; mt++){
          v4f tap = __builtin_amdgcn_mfma_f32_16x16x32_bf16(a[mt], b[nt], zero, 0, 0, 0);
          acc[mt][nt] += tap * wk;
        }
      }
    }
  }
  float a_s = pa[0];
#pragma unroll
  for (int mt = 0; mt < 4; mt++){
#pragma unroll
    for (int nt = 0; nt < 4; nt++){
      int n = vb + nt * 16 + col;
      float bb_base = 0.f; // bias read per r below (o varies)
      (void)bb_base;
#pragma unroll
      for (int r = 0; r < 4; r++){
        int o = mt * 16 + kg * 4 + r;
        float val = acc[mt][nt][r] + s_bias[ki4[nt] * 64 + o];
        val = (val >= 0.f) ? val : a_s * val;
        val += x[(size_t)o * NVOX + n];
        out[(size_t)o * NVOX + n] = val;
      }
    }
  }
}

extern "C" void kernel_launch(void* const* d_in, const int* in_sizes, int n_in,
                              void* d_out, int out_size, void* d_ws, size_t ws_size,
                              hipStream_t stream){
  const float* x    = (const float*)d_in[0];
  const float* pw   = (const float*)d_in[1];
  const float* bw   = (const float*)d_in[2];
  const float* gkw1 = (const float*)d_in[3];
  const float* gkb1 = (const float*)d_in[4];
  const float* gkw2 = (const float*)d_in[5];
  const float* gkb2 = (const float*)d_in[6];
  const float* gkw3 = (const float*)d_in[7];
  const float* gkb3 = (const float*)d_in[8];
  const float* gbw1 = (const float*)d_in[9];
  const float* gbb1 = (const float*)d_in[10];
  const float* gbw2 = (const float*)d_in[11];
  const float* gbb2 = (const float*)d_in[12];
  const float* gbw3 = (const float*)d_in[13];
  const float* gbb3 = (const float*)d_in[14];
  const float* pa   = (const float*)d_in[15];
  float* outp = (float*)d_out;

  float* ws  = (float*)d_ws;
  float* XP  = ws;                                   // 4,096,000 f
  float* BU1 = ws + 4096000;                         // 4,096,000 f
  float* BU2 = ws + 8192000;                         // 4,096,000 f
  short* XPT = (short*)(ws + 12288000);              // 4,741,632 s (16B aligned)
  short* BWB = (short*)(ws + 12288000 + 2370816);    // 110,592 s
  float* KM  = ws + 12288000 + 2370816 + 55296;      // 12*260 f
  float* WI  = KM + 3120;                            // 108 f
  float* BIAS= WI + 108;                             // 256 f
  int*   IDX = (int*)(BIAS + 256);                   // 64,000 i

  hipMemsetAsync(XPT, 0, (size_t)NPAD * 64 * 2, stream);
  proj_k<<<250, 256, 0, stream>>>(x, pw, XP, XPT);
  bwprep_k<<<432, 256, 0, stream>>>(bw, BWB);
  boxw_k<<<16000, 256, 0, stream>>>(XP, BU1);
  boxh_k<<<16000, 256, 0, stream>>>(BU1, BU2);
  boxd_k<<<16000, 256, 0, stream>>>(BU2, BU1);
  kinit_k<<<1, 256, 0, stream>>>(BU1, KM);
  for (int i = 0; i <= 10; i++)
    assign_k<<<250, 256, 0, stream>>>(BU1, KM + i * 260, KM + (i + 1) * 260, IDX, (i == 10) ? 1 : 0);
  mlp_k<<<1, 256, 0, stream>>>(KM + 10 * 260,
                               gkw1, gkb1, gkw2, gkb2, gkw3, gkb3,
                               gbw1, gbb1, gbw2, gbb2, gbw3, gbb3,
                               WI, BIAS);
  conv_k<<<500, 128, 0, stream>>>(XPT, BWB, WI, BIAS, IDX, x, pa, outp);
}